// Round 9
// baseline (334.844 us; speedup 1.0000x reference)
//
#include <hip/hip_runtime.h>
#include <math.h>

// UnifiedCTNN: B=512, N=64, D=2, NODE_H=EDGE_H=32, STEPS=2, JH=16
// Round 9: round-8 arithmetic (280 us, tanh/issue-bound at 2 waves/SIMD) with
// ONE structural change: 512-thread blocks (8 waves) -> 16 waves/CU resident
// (was 8). Each wave now covers 8 j's; reductions widen to 8 chunks.

constexpr float SQRT_OMEGA  = 1.0f;
constexpr float ELL2        = 1.0f;
constexpr float GAMMA_PARA  = 1.0f/3.0f;
constexpr float GAMMA_APARA = 1.0f;

typedef float f32x16 __attribute__((ext_vector_type(16)));
typedef short s16x8  __attribute__((ext_vector_type(8)));
typedef unsigned u32x2 __attribute__((ext_vector_type(2)));

__device__ __forceinline__ float ftanh(float x) {
    float e = __expf(2.0f*x);
    return 1.0f - 2.0f/(e + 1.0f);
}

__device__ __forceinline__ unsigned cvtpk(float lo, float hi) {
    unsigned r;
    asm("v_cvt_pk_bf16_f32 %0, %1, %2" : "=v"(r) : "v"(lo), "v"(hi));
    return r;
}

__device__ __forceinline__ s16x8 frag4(unsigned a, unsigned b, unsigned c, unsigned d) {
    union { unsigned u[4]; s16x8 v; } x;
    x.u[0]=a; x.u[1]=b; x.u[2]=c; x.u[3]=d;
    return x.v;
}

#define MFMA(a,b,c) __builtin_amdgcn_mfma_f32_32x32x16_bf16(a,b,c,0,0,0)

// ---- k_weights: combined matrices + transposed nu/W2 tables ----
__global__ void k_weights(const float* __restrict__ edge_W, const float* __restrict__ rho_ve_W,
                          const float* __restrict__ eu_W1, const float* __restrict__ eu_W2,
                          const float* __restrict__ eu_b2, const float* __restrict__ rho_ev_W,
                          const float* __restrict__ nu_W1, const float* __restrict__ nu_W2,
                          float* __restrict__ MiT0, float* __restrict__ MjT0,
                          float* __restrict__ NiT1, float* __restrict__ NjT1,
                          float* __restrict__ K1T,  float* __restrict__ R0T,
                          float* __restrict__ R1T,  float* __restrict__ rb0,
                          float* __restrict__ rb1,  float* __restrict__ u0c1,
                          float* __restrict__ W1T0, float* __restrict__ W1T1,
                          float* __restrict__ W2T0, float* __restrict__ W2T1)
{
    int t = blockIdx.x*256 + threadIdx.x;         // 1024 threads
    if (t >= 1024) return;
    int k = t >> 5, eo = t & 31;
    float mi=0.f, mj=0.f, ni=0.f, nj=0.f, k1=0.f;
    for (int a = 0; a < 32; ++a) {
        float w1h = eu_W1[eo*96 + a];
        mi += w1h*edge_W[a*65 + 1 + k];
        mj += w1h*edge_W[a*65 + 33 + k];
        float r0 = rho_ve_W[a*32 + k];
        mi += eu_W1[eo*96 + 32 + a]*r0;
        mj += eu_W1[eo*96 + 64 + a]*r0;
        float r1v = rho_ve_W[1024 + a*32 + k];
        ni += eu_W1[3072 + eo*96 + 32 + a]*r1v;
        nj += eu_W1[3072 + eo*96 + 64 + a]*r1v;
        k1 += eu_W1[3072 + eo*96 + a]*eu_W2[a*32 + k];
    }
    MiT0[t]=mi; MjT0[t]=mj; NiT1[t]=ni; NjT1[t]=nj; K1T[t]=k1;
    {   // R matrices, transposed
        int a = t >> 5, kk = t & 31;
        float r0a=0.f, r1a=0.f;
        for (int e = 0; e < 32; ++e) {
            r0a += rho_ev_W[a*32 + e]*eu_W2[e*32 + kk];
            r1a += rho_ev_W[1024 + a*32 + e]*eu_W2[1024 + e*32 + kk];
        }
        R0T[kk*32 + a] = r0a;
        R1T[kk*32 + a] = r1a;
    }
    {   // nu transposes
        int kk = t >> 5, hh = t & 31;
        W1T0[t]        = nu_W1[hh*64 + kk];
        W1T0[1024 + t] = nu_W1[hh*64 + 32 + kk];
        W1T1[t]        = nu_W1[2048 + hh*64 + kk];
        W1T1[1024 + t] = nu_W1[2048 + hh*64 + 32 + kk];
        W2T0[t]        = nu_W2[hh*32 + kk];
        W2T1[t]        = nu_W2[1024 + hh*32 + kk];
    }
    if (t < 32) {
        float u=0.f, c=0.f, b0=0.f, b1v=0.f;
        for (int kk = 0; kk < 32; ++kk) {
            u   += eu_W1[t*96 + kk]*edge_W[kk*65];
            c   += eu_W1[3072 + t*96 + kk]*eu_b2[kk];
            b0  += rho_ev_W[t*32 + kk]*eu_b2[kk];
            b1v += rho_ev_W[1024 + t*32 + kk]*eu_b2[32 + kk];
        }
        u0c1[t] = u; u0c1[32+t] = c;
        rb0[t] = 64.f*b0; rb1[t] = 64.f*b1v;
    }
}

// ---- k_fused: one block (512 thr, 8 waves) = one batch element ----
// LDS map as rounds 6-8 (50.9 KB -> 2 blocks/CU, 16 waves/CU).
// Epilogue scratch (aliases dead TI0): PART[16][33]=128..656, RED 656..1168,
// T1F 1168, HVM 1200, HEM 1232  (TI0 spans 128..2208).
__launch_bounds__(512)
__global__ void k_fused(const float* __restrict__ x, const int* __restrict__ spin,
                        const float* __restrict__ node_W,
                        const float* __restrict__ eu_b1, const float* __restrict__ eu_W2,
                        const float* __restrict__ eu_b2,
                        const float* __restrict__ MiT0, const float* __restrict__ MjT0,
                        const float* __restrict__ NiT1, const float* __restrict__ NjT1,
                        const float* __restrict__ K1T,  const float* __restrict__ u0c1,
                        const float* __restrict__ R0T,  const float* __restrict__ R1T,
                        const float* __restrict__ rb0,  const float* __restrict__ rb1,
                        const float* __restrict__ W1T0, const float* __restrict__ W1T1,
                        const float* __restrict__ W2T0, const float* __restrict__ W2T1,
                        const float* __restrict__ nu_b1, const float* __restrict__ nu_b2,
                        const float* __restrict__ dx_W, const float* __restrict__ bf_scale,
                        const float* __restrict__ f_W1, const float* __restrict__ f_b1,
                        const float* __restrict__ f_W2, const float* __restrict__ f_b2,
                        float* __restrict__ dx_out, float* __restrict__ f_out)
{
    constexpr int X    = 0;
    constexpr int TI0  = 128;
    constexpr int TJ0  = 2208;
    constexpr int HV   = 4288;
    constexpr int SS   = 6400;
    constexpr int MM   = 8512;      // == TI1
    constexpr int HD   = 10624;     // == TJ1
    constexpr int TI1  = MM;
    constexpr int TJ1  = HD;
    constexpr int PART = 128;       // [16][33] aliases TI0 (dead after edge1)
    constexpr int RED  = 656;       // [512]
    constexpr int T1F  = 1168;
    constexpr int HVM  = 1200;
    constexpr int HEM  = 1232;
    __shared__ float sm[12736];
    __shared__ int   sp[64];

    const int tid = threadIdx.x;
    const int b   = blockIdx.x;
    const int i   = tid & 63;      // lane = node row i
    const int c   = tid >> 6;      // wave id = j-chunk (0..7), 8 j's each
    const int h   = i >> 5;        // lane half
    const int n   = i & 31;        // lane-in-half; e-channel in D'-layout

    if (tid < 128) sm[X + tid] = x[b*128 + tid]*SQRT_OMEGA;
    if (tid < 64)  sp[tid] = spin[tid];
    __syncthreads();

    // hv0[n][k] = x_sc[n] . node_W[k]
    for (int out = tid; out < 2048; out += 512) {
        int nn = out >> 5, k = out & 31;
        sm[HV + nn*33 + k] = sm[X + 2*nn]*node_W[k*2] + sm[X + 2*nn + 1]*node_W[k*2+1];
    }
    __syncthreads();

    // TI0/TJ0 tables from hv0
    for (int out = tid; out < 2048; out += 512) {
        int nn = out & 63, e = out >> 6;
        float ai = eu_b1[e], aj = 0.f;
        #pragma unroll
        for (int k = 0; k < 32; ++k) {
            float hvv = sm[HV + nn*33 + k];
            ai += MiT0[k*32 + e]*hvv;
            aj += MjT0[k*32 + e]*hvv;
        }
        sm[TI0 + e*65 + nn] = ai;
        sm[TJ0 + e*65 + nn] = aj;
    }
    __syncthreads();

    const float xi0 = sm[X + 2*i], xi1 = sm[X + 2*i + 1];

    // ---- edge loop 0 (VALU path) ----
    {
        float S0[32];
        #pragma unroll
        for (int e = 0; e < 32; ++e) S0[e] = 0.f;
        #pragma unroll 1
        for (int jl = 0; jl < 8; ++jl) {
            const int j = c*8 + jl;
            float d0 = sm[X + 2*j] - xi0;
            float d1 = sm[X + 2*j + 1] - xi1;
            float r1 = sqrtf(d0*d0 + d1*d1 + 1e-12f);
            #pragma unroll
            for (int e = 0; e < 32; ++e)
                S0[e] += ftanh(fmaf(r1, u0c1[e], sm[TI0 + e*65 + i] + sm[TJ0 + e*65 + j]));
        }
        __syncthreads();
        for (int cc = 0; cc < 8; ++cc) {
            if (c == cc) {
                #pragma unroll
                for (int e = 0; e < 32; ++e) {
                    if (cc == 0) sm[SS + i*33 + e]  = S0[e];
                    else         sm[SS + i*33 + e] += S0[e];
                }
            }
            __syncthreads();
        }
    }

    // ---- node update 0: hv1 = nu0(hv0, R0@S + rb0) -> HV ----
    for (int out = tid; out < 2048; out += 512) {
        int nn = out >> 5, a = out & 31;
        float acc = rb0[a];
        #pragma unroll
        for (int k = 0; k < 32; ++k) acc += sm[SS + nn*33 + k]*R0T[k*32 + a];
        sm[MM + nn*33 + a] = acc;
    }
    __syncthreads();
    for (int out = tid; out < 2048; out += 512) {
        int nn = out >> 5, hh = out & 31;
        float acc = nu_b1[hh];
        #pragma unroll
        for (int k = 0; k < 32; ++k) acc += sm[HV + nn*33 + k]*W1T0[k*32 + hh];
        #pragma unroll
        for (int k = 0; k < 32; ++k) acc += sm[MM + nn*33 + k]*W1T0[(32+k)*32 + hh];
        sm[HD + nn*33 + hh] = ftanh(acc);
    }
    __syncthreads();
    for (int out = tid; out < 2048; out += 512) {
        int nn = out >> 5, oo = out & 31;
        float acc = nu_b2[oo];
        #pragma unroll
        for (int k = 0; k < 32; ++k) acc += sm[HD + nn*33 + k]*W2T0[k*32 + oo];
        sm[HV + nn*33 + oo] = acc;                 // HV now holds hv1
    }
    __syncthreads();

    // TI1/TJ1 tables from hv1 (into MM/HD — m/hid dead here)
    for (int out = tid; out < 2048; out += 512) {
        int nn = out & 63, e = out >> 6;
        float ai = eu_b1[32 + e] + u0c1[32 + e], aj = 0.f;
        #pragma unroll
        for (int k = 0; k < 32; ++k) {
            float hvv = sm[HV + nn*33 + k];
            ai += NiT1[k*32 + e]*hvv;
            aj += NjT1[k*32 + e]*hvv;
        }
        sm[TI1 + e*65 + nn] = ai;
        sm[TJ1 + e*65 + nn] = aj;
    }
    __syncthreads();

    // ---- edge loop 1: MFMA for K1@t0 (D'[edge][e], e = n lane) ----
    {
        s16x8 B1f, B2f;
        {
            unsigned bw[8];
            #pragma unroll
            for (int v = 0; v < 4; ++v) {
                bw[v]   = cvtpk(K1T[(8*h + 2*v)*32 + n],      K1T[(8*h + 2*v + 1)*32 + n]);
                bw[4+v] = cvtpk(K1T[(16 + 8*h + 2*v)*32 + n], K1T[(16 + 8*h + 2*v + 1)*32 + n]);
            }
            B1f = frag4(bw[0],bw[1],bw[2],bw[3]);
            B2f = frag4(bw[4],bw[5],bw[6],bw[7]);
        }

        float S1a[16], S1b[16];
        #pragma unroll
        for (int r = 0; r < 16; ++r) { S1a[r] = 0.f; S1b[r] = 0.f; }
        float t1acc0 = 0.f, t1acc1 = 0.f;

        #pragma unroll 1
        for (int jl = 0; jl < 8; ++jl) {
            const int j = c*8 + jl;
            float d0 = sm[X + 2*j] - xi0;
            float d1 = sm[X + 2*j + 1] - xi1;
            float r1 = sqrtf(d0*d0 + d1*d1 + 1e-12f);

            unsigned w[16];
            #pragma unroll
            for (int q = 0; q < 16; ++q) {
                int e0 = 2*q, e1 = 2*q + 1;
                float ta = ftanh(fmaf(r1, u0c1[e0], sm[TI0 + e0*65 + i] + sm[TJ0 + e0*65 + j]));
                float tb = ftanh(fmaf(r1, u0c1[e1], sm[TI0 + e1*65 + i] + sm[TJ0 + e1*65 + j]));
                w[q] = cvtpk(ta, tb);
            }
            unsigned a10[4], a11[4], a20[4], a21[4];
            #pragma unroll
            for (int v = 0; v < 4; ++v) {
                u32x2 ra = __builtin_amdgcn_permlane32_swap(w[v],   w[4+v],  false, false);
                a10[v] = ra[0]; a11[v] = ra[1];
                u32x2 rb = __builtin_amdgcn_permlane32_swap(w[8+v], w[12+v], false, false);
                a20[v] = rb[0]; a21[v] = rb[1];
            }
            float tj1v = sm[TJ1 + n*65 + j];
            f32x16 acc0, acc1;
            #pragma unroll
            for (int r = 0; r < 16; ++r) {
                int m = (r&3) + 8*(r>>2) + 4*h;
                acc0[r] = sm[TI1 + n*65 + m]      + tj1v;
                acc1[r] = sm[TI1 + n*65 + 32 + m] + tj1v;
            }
            acc0 = MFMA(frag4(a10[0],a10[1],a10[2],a10[3]), B1f, acc0);
            acc0 = MFMA(frag4(a20[0],a20[1],a20[2],a20[3]), B2f, acc0);
            acc1 = MFMA(frag4(a11[0],a11[1],a11[2],a11[3]), B1f, acc1);
            acc1 = MFMA(frag4(a21[0],a21[1],a21[2],a21[3]), B2f, acc1);
            #pragma unroll
            for (int r = 0; r < 16; ++r) {
                int m = (r&3) + 8*(r>>2) + 4*h;
                float t1a = ftanh(acc0[r]);
                float t1b = ftanh(acc1[r]);
                S1a[r] += t1a;
                S1b[r] += t1b;
                if (j > m)      t1acc0 += t1a;
                if (j > 32 + m) t1acc1 += t1b;
            }
        }
        __syncthreads();                 // all waves done with TI0/TJ0/TI1/TJ1

        // T1 partials into PART (aliases dead TI0)
        {
            float tf = t1acc0 + t1acc1;
            tf += __shfl_xor(tf, 32, 64);
            if (i < 32) sm[PART + c*33 + i] = tf;
        }
        // S1 -> SS across the 8 waves
        for (int cc = 0; cc < 8; ++cc) {
            if (c == cc) {
                #pragma unroll
                for (int r = 0; r < 16; ++r) {
                    int m = (r&3) + 8*(r>>2) + 4*h;
                    if (cc == 0) {
                        sm[SS + m*33 + n]        = S1a[r];
                        sm[SS + (32+m)*33 + n]   = S1b[r];
                    } else {
                        sm[SS + m*33 + n]       += S1a[r];
                        sm[SS + (32+m)*33 + n]  += S1b[r];
                    }
                }
            }
            __syncthreads();
        }
        if (tid < 32) {
            float tot = 0.f;
            #pragma unroll
            for (int g = 0; g < 8; ++g) tot += sm[PART + g*33 + tid];
            sm[T1F + tid] = tot;
        }
        __syncthreads();
    }

    // ---- node update 1: hv2 = nu1(hv1, R1@S + rb1) -> MM ----
    for (int out = tid; out < 2048; out += 512) {
        int nn = out >> 5, a = out & 31;
        float acc = rb1[a];
        #pragma unroll
        for (int k = 0; k < 32; ++k) acc += sm[SS + nn*33 + k]*R1T[k*32 + a];
        sm[MM + nn*33 + a] = acc;
    }
    __syncthreads();
    for (int out = tid; out < 2048; out += 512) {
        int nn = out >> 5, hh = out & 31;
        float acc = nu_b1[32 + hh];
        #pragma unroll
        for (int k = 0; k < 32; ++k) acc += sm[HV + nn*33 + k]*W1T1[k*32 + hh];
        #pragma unroll
        for (int k = 0; k < 32; ++k) acc += sm[MM + nn*33 + k]*W1T1[(32+k)*32 + hh];
        sm[HD + nn*33 + hh] = ftanh(acc);
    }
    __syncthreads();
    for (int out = tid; out < 2048; out += 512) {
        int nn = out >> 5, oo = out & 31;
        float acc = nu_b2[32 + oo];
        #pragma unroll
        for (int k = 0; k < 32; ++k) acc += sm[HD + nn*33 + k]*W2T1[k*32 + oo];
        sm[MM + nn*33 + oo] = acc;                 // MM now holds hv2
    }
    __syncthreads();

    // ---- dx output + hvm partials ----
    if (tid < 128) {
        int nn = tid >> 1, d = tid & 1;
        float scale = log1pf(__expf(bf_scale[0]));
        float a = 0.f;
        #pragma unroll
        for (int k = 0; k < 32; ++k) a += sm[MM + nn*33 + k]*dx_W[d*32 + k];
        dx_out[(b*64 + nn)*2 + d] = scale*ftanh(a);
    }
    {
        int e = tid & 31, g = tid >> 5;     // g = 0..15, 4 rows each
        float p = 0.f;
        #pragma unroll
        for (int r = 0; r < 4; ++r) p += sm[MM + (g*4 + r)*33 + e];
        sm[PART + g*33 + e] = p;
    }
    __syncthreads();
    if (tid < 32) {
        float s = 0.f;
        #pragma unroll
        for (int g = 0; g < 16; ++g) s += sm[PART + g*33 + tid];
        sm[HVM + tid] = s*(1.0f/64.0f);
        float he = 0.f;
        #pragma unroll
        for (int k = 0; k < 32; ++k) he += eu_W2[1024 + tid*32 + k]*sm[T1F + k];
        sm[HEM + tid] = he*(1.0f/2016.0f) + eu_b2[32 + tid];
    }

    // ---- pair statistics + f head ----
    float rsum = 0.f, cusp = 0.f, env = 0.f;
    for (int idx = tid; idx < 4096; idx += 512) {
        int ii = idx >> 6, jj = idx & 63;
        if (ii < jj) {
            float d0 = sm[X + ii*2] - sm[X + jj*2];
            float d1 = sm[X + ii*2 + 1] - sm[X + jj*2 + 1];
            float r2 = d0*d0 + d1*d1;
            rsum += sqrtf(r2 + 1e-12f);
            float rp = sqrtf(r2 + 1e-30f);
            float gamma = (sp[ii] == sp[jj]) ? GAMMA_PARA : GAMMA_APARA;
            cusp += gamma*rp/(1.0f + rp*SQRT_OMEGA);
        }
    }
    if (tid < 128) { float v = sm[X + tid]; env = v*v; }

    auto blockReduce = [&](float v) -> float {
        sm[RED + tid] = v; __syncthreads();
        for (int s = 256; s > 0; s >>= 1) {
            if (tid < s) sm[RED + tid] += sm[RED + tid + s];
            __syncthreads();
        }
        float r = sm[RED]; __syncthreads(); return r;
    };
    float rtot = blockReduce(rsum);
    float ctot = blockReduce(cusp);
    float etot = blockReduce(env);

    if (tid < 16) {
        float r2m = rtot*(1.0f/2016.0f);
        float envelope = __expf(-0.5f*etot/ELL2);
        float acc = f_b1[tid];
        #pragma unroll
        for (int m2 = 0; m2 < 32; ++m2) acc += sm[HVM + m2]*f_W1[tid*65 + m2];
        #pragma unroll
        for (int m2 = 0; m2 < 32; ++m2) acc += sm[HEM + m2]*f_W1[tid*65 + 32 + m2];
        acc += r2m*f_W1[tid*65 + 64];
        float v = ftanh(acc)*f_W2[tid];
        v += __shfl_xor(v, 8, 64);
        v += __shfl_xor(v, 4, 64);
        v += __shfl_xor(v, 2, 64);
        v += __shfl_xor(v, 1, 64);
        if (tid == 0) f_out[b] = (v + f_b2[0])*envelope + 0.2f*ctot;
    }
}

extern "C" void kernel_launch(void* const* d_in, const int* in_sizes, int n_in,
                              void* d_out, int out_size, void* d_ws, size_t ws_size,
                              hipStream_t stream)
{
    (void)in_sizes; (void)n_in; (void)out_size; (void)ws_size;
    const float* x         = (const float*)d_in[0];
    const int*   spin      = (const int*)d_in[1];
    const float* node_W    = (const float*)d_in[2];
    const float* edge_W    = (const float*)d_in[3];
    const float* rho_ve_W  = (const float*)d_in[4];
    const float* eu_W1     = (const float*)d_in[5];
    const float* eu_b1     = (const float*)d_in[6];
    const float* eu_W2     = (const float*)d_in[7];
    const float* eu_b2     = (const float*)d_in[8];
    const float* rho_ev_W  = (const float*)d_in[9];
    const float* nu_W1     = (const float*)d_in[10];
    const float* nu_b1     = (const float*)d_in[11];
    const float* nu_W2     = (const float*)d_in[12];
    const float* nu_b2     = (const float*)d_in[13];
    const float* dx_W      = (const float*)d_in[14];
    const float* bf_scale  = (const float*)d_in[15];
    const float* f_W1      = (const float*)d_in[16];
    const float* f_b1      = (const float*)d_in[17];
    const float* f_W2      = (const float*)d_in[18];
    const float* f_b2      = (const float*)d_in[19];

    float* ws    = (float*)d_ws;
    float* MiT0  = ws;                       // 1024 each
    float* MjT0  = MiT0 + 1024;
    float* NiT1  = MjT0 + 1024;
    float* NjT1  = NiT1 + 1024;
    float* K1T   = NjT1 + 1024;
    float* R0T   = K1T  + 1024;
    float* R1T   = R0T  + 1024;
    float* W1T0  = R1T  + 1024;              // 2048 each
    float* W1T1  = W1T0 + 2048;
    float* W2T0  = W1T1 + 2048;              // 1024 each
    float* W2T1  = W2T0 + 1024;
    float* rb0   = W2T1 + 1024;              // 32
    float* rb1   = rb0  + 32;                // 32
    float* u0c1  = rb1  + 32;                // 64

    float* dxout = (float*)d_out;
    float* fout  = dxout + 512*64*2;

    k_weights<<<4, 256, 0, stream>>>(edge_W, rho_ve_W, eu_W1, eu_W2, eu_b2, rho_ev_W,
                                     nu_W1, nu_W2,
                                     MiT0, MjT0, NiT1, NjT1, K1T, R0T, R1T,
                                     rb0, rb1, u0c1, W1T0, W1T1, W2T0, W2T1);
    k_fused<<<512, 512, 0, stream>>>(x, spin, node_W, eu_b1, eu_W2, eu_b2,
                                     MiT0, MjT0, NiT1, NjT1, K1T, u0c1,
                                     R0T, R1T, rb0, rb1, W1T0, W1T1, W2T0, W2T1,
                                     nu_b1, nu_b2, dx_W, bf_scale,
                                     f_W1, f_b1, f_W2, f_b2, dxout, fout);
}

// Round 10
// 208.843 us; speedup vs baseline: 1.6033x; 1.6033x over previous
//
#include <hip/hip_runtime.h>
#include <math.h>

// UnifiedCTNN: B=512, N=64, D=2, NODE_H=EDGE_H=32, STEPS=2, JH=16
// Round 10: revert to round-8 structure (256 thr, 280 us) + instruction diet:
//  (a) TI0/TJ0 -> [node][36] rows, read as 8x ds_read_b128; TI0/TI1 rows
//      hoisted to registers (j-invariant).
//  (b) tanh-scale folded into tables/weights (x 2*log2e) so
//      tanh = 1 - 2*rcp(1 + v_exp(q)) with no inner multiply.

constexpr float SQRT_OMEGA  = 1.0f;
constexpr float ELL2        = 1.0f;
constexpr float GAMMA_PARA  = 1.0f/3.0f;
constexpr float GAMMA_APARA = 1.0f;
constexpr float C2LOG2E     = 2.8853900817779268f;   // 2*log2(e)

typedef float f32x16 __attribute__((ext_vector_type(16)));
typedef short s16x8  __attribute__((ext_vector_type(8)));
typedef unsigned u32x2 __attribute__((ext_vector_type(2)));

__device__ __forceinline__ float ftanh(float x) {          // plain tanh (dx/f head)
    float e = __expf(2.0f*x);
    return 1.0f - 2.0f/(e + 1.0f);
}

// tanh with the 2*log2e scale pre-folded into q: tanh = 1 - 2/(1+2^q)
__device__ __forceinline__ float tanhE(float q) {
    float E, r;
    asm("v_exp_f32 %0, %1" : "=v"(E) : "v"(q));
    float d = 1.0f + E;
    asm("v_rcp_f32 %0, %1" : "=v"(r) : "v"(d));
    return fmaf(-2.0f, r, 1.0f);
}

__device__ __forceinline__ unsigned cvtpk(float lo, float hi) {
    unsigned r;
    asm("v_cvt_pk_bf16_f32 %0, %1, %2" : "=v"(r) : "v"(lo), "v"(hi));
    return r;
}

__device__ __forceinline__ s16x8 frag4(unsigned a, unsigned b, unsigned c, unsigned d) {
    union { unsigned u[4]; s16x8 v; } x;
    x.u[0]=a; x.u[1]=b; x.u[2]=c; x.u[3]=d;
    return x.v;
}

#define MFMA(a,b,c) __builtin_amdgcn_mfma_f32_32x32x16_bf16(a,b,c,0,0,0)

// ---- k_weights: combined matrices + transposed nu/W2 tables ----
// u0 and K1T and W1T* are prescaled by C2LOG2E (tanh-input domain).
__global__ void k_weights(const float* __restrict__ edge_W, const float* __restrict__ rho_ve_W,
                          const float* __restrict__ eu_W1, const float* __restrict__ eu_W2,
                          const float* __restrict__ eu_b2, const float* __restrict__ rho_ev_W,
                          const float* __restrict__ nu_W1, const float* __restrict__ nu_W2,
                          float* __restrict__ MiT0, float* __restrict__ MjT0,
                          float* __restrict__ NiT1, float* __restrict__ NjT1,
                          float* __restrict__ K1T,  float* __restrict__ R0T,
                          float* __restrict__ R1T,  float* __restrict__ rb0,
                          float* __restrict__ rb1,  float* __restrict__ u0c1,
                          float* __restrict__ W1T0, float* __restrict__ W1T1,
                          float* __restrict__ W2T0, float* __restrict__ W2T1)
{
    int t = blockIdx.x*256 + threadIdx.x;         // 1024 threads
    if (t >= 1024) return;
    int k = t >> 5, eo = t & 31;
    float mi=0.f, mj=0.f, ni=0.f, nj=0.f, k1=0.f;
    for (int a = 0; a < 32; ++a) {
        float w1h = eu_W1[eo*96 + a];
        mi += w1h*edge_W[a*65 + 1 + k];
        mj += w1h*edge_W[a*65 + 33 + k];
        float r0 = rho_ve_W[a*32 + k];
        mi += eu_W1[eo*96 + 32 + a]*r0;
        mj += eu_W1[eo*96 + 64 + a]*r0;
        float r1v = rho_ve_W[1024 + a*32 + k];
        ni += eu_W1[3072 + eo*96 + 32 + a]*r1v;
        nj += eu_W1[3072 + eo*96 + 64 + a]*r1v;
        k1 += eu_W1[3072 + eo*96 + a]*eu_W2[a*32 + k];
    }
    MiT0[t]=mi; MjT0[t]=mj; NiT1[t]=ni; NjT1[t]=nj;
    K1T[t]=k1*C2LOG2E;
    {   // R matrices, transposed
        int a = t >> 5, kk = t & 31;
        float r0a=0.f, r1a=0.f;
        for (int e = 0; e < 32; ++e) {
            r0a += rho_ev_W[a*32 + e]*eu_W2[e*32 + kk];
            r1a += rho_ev_W[1024 + a*32 + e]*eu_W2[1024 + e*32 + kk];
        }
        R0T[kk*32 + a] = r0a;
        R1T[kk*32 + a] = r1a;
    }
    {   // nu transposes (W1 prescaled: feeds tanhE)
        int kk = t >> 5, hh = t & 31;
        W1T0[t]        = nu_W1[hh*64 + kk]*C2LOG2E;
        W1T0[1024 + t] = nu_W1[hh*64 + 32 + kk]*C2LOG2E;
        W1T1[t]        = nu_W1[2048 + hh*64 + kk]*C2LOG2E;
        W1T1[1024 + t] = nu_W1[2048 + hh*64 + 32 + kk]*C2LOG2E;
        W2T0[t]        = nu_W2[hh*32 + kk];
        W2T1[t]        = nu_W2[1024 + hh*32 + kk];
    }
    if (t < 32) {
        float u=0.f, c=0.f, b0=0.f, b1v=0.f;
        for (int kk = 0; kk < 32; ++kk) {
            u   += eu_W1[t*96 + kk]*edge_W[kk*65];
            c   += eu_W1[3072 + t*96 + kk]*eu_b2[kk];
            b0  += rho_ev_W[t*32 + kk]*eu_b2[kk];
            b1v += rho_ev_W[1024 + t*32 + kk]*eu_b2[32 + kk];
        }
        u0c1[t] = u*C2LOG2E;        // prescaled (only used in t0 pre-activation)
        u0c1[32+t] = c;             // raw; scaled inside TI1 build
        rb0[t] = 64.f*b0; rb1[t] = 64.f*b1v;
    }
}

// ---- k_fused: one block (256 thr) = one batch element ----
// LDS map (floats), all offsets %4==0, sm 16B-aligned:
//   X    0     (128)
//   TI0  128   [64][36] (scaled)  == epilogue scratch after edge1
//   TJ0  2432  [64][36] (scaled)
//   HV   4736  [64][33]
//   SS   6848  [64][33]
//   MM   8960  [64][33] == TI1 [32][65] (scaled, 2080<=2112)
//   HD   11072 region 2304: hid [64][33] == TJ1 [64][36] (scaled)
// total 13376 floats = 52.25 KB
__launch_bounds__(256)
__global__ void k_fused(const float* __restrict__ x, const int* __restrict__ spin,
                        const float* __restrict__ node_W,
                        const float* __restrict__ eu_b1, const float* __restrict__ eu_W2,
                        const float* __restrict__ eu_b2,
                        const float* __restrict__ MiT0, const float* __restrict__ MjT0,
                        const float* __restrict__ NiT1, const float* __restrict__ NjT1,
                        const float* __restrict__ K1T,  const float* __restrict__ u0c1,
                        const float* __restrict__ R0T,  const float* __restrict__ R1T,
                        const float* __restrict__ rb0,  const float* __restrict__ rb1,
                        const float* __restrict__ W1T0, const float* __restrict__ W1T1,
                        const float* __restrict__ W2T0, const float* __restrict__ W2T1,
                        const float* __restrict__ nu_b1, const float* __restrict__ nu_b2,
                        const float* __restrict__ dx_W, const float* __restrict__ bf_scale,
                        const float* __restrict__ f_W1, const float* __restrict__ f_b1,
                        const float* __restrict__ f_W2, const float* __restrict__ f_b2,
                        float* __restrict__ dx_out, float* __restrict__ f_out)
{
    constexpr int X    = 0;
    constexpr int TI0  = 128;
    constexpr int TJ0  = 2432;
    constexpr int HV   = 4736;
    constexpr int SS   = 6848;
    constexpr int MM   = 8960;
    constexpr int HD   = 11072;
    constexpr int TI1  = MM;
    constexpr int TJ1  = HD;
    constexpr int PART = 128;       // aliases TI0 (dead after edge1 j-loop)
    constexpr int RED  = 392;
    constexpr int T1F  = 648;
    constexpr int HVM  = 680;
    constexpr int HEM  = 712;
    __shared__ __align__(16) float sm[13376];
    __shared__ int sp[64];

    const int tid = threadIdx.x;
    const int b   = blockIdx.x;
    const int i   = tid & 63;      // lane = node row i
    const int c   = tid >> 6;      // wave id = j-chunk
    const int h   = i >> 5;        // lane half
    const int n   = i & 31;        // e-channel in D'-layout

    if (tid < 128) sm[X + tid] = x[b*128 + tid]*SQRT_OMEGA;
    if (tid < 64)  sp[tid] = spin[tid];
    __syncthreads();

    // hv0[n][k] = x_sc[n] . node_W[k]
    for (int out = tid; out < 2048; out += 256) {
        int nn = out >> 5, k = out & 31;
        sm[HV + nn*33 + k] = sm[X + 2*nn]*node_W[k*2] + sm[X + 2*nn + 1]*node_W[k*2+1];
    }
    __syncthreads();

    // TI0/TJ0 tables from hv0 ([node][36] rows, prescaled)
    for (int out = tid; out < 2048; out += 256) {
        int nn = out & 63, e = out >> 6;
        float ai = eu_b1[e], aj = 0.f;
        #pragma unroll
        for (int k = 0; k < 32; ++k) {
            float hvv = sm[HV + nn*33 + k];
            ai += MiT0[k*32 + e]*hvv;
            aj += MjT0[k*32 + e]*hvv;
        }
        sm[TI0 + nn*36 + e] = ai*C2LOG2E;
        sm[TJ0 + nn*36 + e] = aj*C2LOG2E;
    }
    __syncthreads();

    const float xi0 = sm[X + 2*i], xi1 = sm[X + 2*i + 1];

    // ---- edge loop 0 ----
    {
        float ti0v[32];                         // hoisted own-row TI0 (8x b128)
        #pragma unroll
        for (int q = 0; q < 8; ++q) {
            float4 v = *(const float4*)&sm[TI0 + i*36 + 4*q];
            ti0v[4*q]=v.x; ti0v[4*q+1]=v.y; ti0v[4*q+2]=v.z; ti0v[4*q+3]=v.w;
        }
        float S0[32];
        #pragma unroll
        for (int e = 0; e < 32; ++e) S0[e] = 0.f;
        #pragma unroll 1
        for (int jl = 0; jl < 16; ++jl) {
            const int j = c*16 + jl;
            float d0 = sm[X + 2*j] - xi0;
            float d1 = sm[X + 2*j + 1] - xi1;
            float r1 = sqrtf(d0*d0 + d1*d1 + 1e-12f);
            float tj0v[32];
            #pragma unroll
            for (int q = 0; q < 8; ++q) {
                float4 v = *(const float4*)&sm[TJ0 + j*36 + 4*q];
                tj0v[4*q]=v.x; tj0v[4*q+1]=v.y; tj0v[4*q+2]=v.z; tj0v[4*q+3]=v.w;
            }
            #pragma unroll
            for (int e = 0; e < 32; ++e)
                S0[e] += tanhE(fmaf(r1, u0c1[e], ti0v[e] + tj0v[e]));
        }
        __syncthreads();
        for (int cc = 0; cc < 4; ++cc) {
            if (c == cc) {
                #pragma unroll
                for (int e = 0; e < 32; ++e) {
                    if (cc == 0) sm[SS + i*33 + e]  = S0[e];
                    else         sm[SS + i*33 + e] += S0[e];
                }
            }
            __syncthreads();
        }
    }

    // ---- node update 0: hv1 = nu0(hv0, R0@S + rb0) -> HV ----
    for (int out = tid; out < 2048; out += 256) {
        int nn = out >> 5, a = out & 31;
        float acc = rb0[a];
        #pragma unroll
        for (int k = 0; k < 32; ++k) acc += sm[SS + nn*33 + k]*R0T[k*32 + a];
        sm[MM + nn*33 + a] = acc;
    }
    __syncthreads();
    for (int out = tid; out < 2048; out += 256) {
        int nn = out >> 5, hh = out & 31;
        float acc = nu_b1[hh]*C2LOG2E;
        #pragma unroll
        for (int k = 0; k < 32; ++k) acc += sm[HV + nn*33 + k]*W1T0[k*32 + hh];
        #pragma unroll
        for (int k = 0; k < 32; ++k) acc += sm[MM + nn*33 + k]*W1T0[(32+k)*32 + hh];
        sm[HD + nn*33 + hh] = tanhE(acc);
    }
    __syncthreads();
    for (int out = tid; out < 2048; out += 256) {
        int nn = out >> 5, oo = out & 31;
        float acc = nu_b2[oo];
        #pragma unroll
        for (int k = 0; k < 32; ++k) acc += sm[HD + nn*33 + k]*W2T0[k*32 + oo];
        sm[HV + nn*33 + oo] = acc;                 // HV now holds hv1
    }
    __syncthreads();

    // TI1 ([e][65]) / TJ1 ([j][36]) tables from hv1, prescaled
    for (int out = tid; out < 2048; out += 256) {
        int nn = out & 63, e = out >> 6;
        float ai = eu_b1[32 + e] + u0c1[32 + e], aj = 0.f;
        #pragma unroll
        for (int k = 0; k < 32; ++k) {
            float hvv = sm[HV + nn*33 + k];
            ai += NiT1[k*32 + e]*hvv;
            aj += NjT1[k*32 + e]*hvv;
        }
        sm[TI1 + e*65 + nn] = ai*C2LOG2E;
        sm[TJ1 + nn*36 + e] = aj*C2LOG2E;
    }
    __syncthreads();

    // ---- edge loop 1: MFMA for K1@t0 (D'[edge][e], e = n lane) ----
    {
        s16x8 B1f, B2f;
        {
            unsigned bw[8];
            #pragma unroll
            for (int v = 0; v < 4; ++v) {
                bw[v]   = cvtpk(K1T[(8*h + 2*v)*32 + n],      K1T[(8*h + 2*v + 1)*32 + n]);
                bw[4+v] = cvtpk(K1T[(16 + 8*h + 2*v)*32 + n], K1T[(16 + 8*h + 2*v + 1)*32 + n]);
            }
            B1f = frag4(bw[0],bw[1],bw[2],bw[3]);
            B2f = frag4(bw[4],bw[5],bw[6],bw[7]);
        }
        float ti0v[32];                          // hoisted TI0 row (scaled)
        #pragma unroll
        for (int q = 0; q < 8; ++q) {
            float4 v = *(const float4*)&sm[TI0 + i*36 + 4*q];
            ti0v[4*q]=v.x; ti0v[4*q+1]=v.y; ti0v[4*q+2]=v.z; ti0v[4*q+3]=v.w;
        }
        float ti1a[16], ti1b[16];                // hoisted TI1 row (j-invariant)
        #pragma unroll
        for (int r = 0; r < 16; ++r) {
            int m = (r&3) + 8*(r>>2) + 4*h;
            ti1a[r] = sm[TI1 + n*65 + m];
            ti1b[r] = sm[TI1 + n*65 + 32 + m];
        }

        float S1a[16], S1b[16];
        #pragma unroll
        for (int r = 0; r < 16; ++r) { S1a[r] = 0.f; S1b[r] = 0.f; }
        float t1acc0 = 0.f, t1acc1 = 0.f;

        #pragma unroll 1
        for (int jl = 0; jl < 16; ++jl) {
            const int j = c*16 + jl;
            float d0 = sm[X + 2*j] - xi0;
            float d1 = sm[X + 2*j + 1] - xi1;
            float r1 = sqrtf(d0*d0 + d1*d1 + 1e-12f);

            float tj0v[32];
            #pragma unroll
            for (int q = 0; q < 8; ++q) {
                float4 v = *(const float4*)&sm[TJ0 + j*36 + 4*q];
                tj0v[4*q]=v.x; tj0v[4*q+1]=v.y; tj0v[4*q+2]=v.z; tj0v[4*q+3]=v.w;
            }
            unsigned w[16];
            #pragma unroll
            for (int q = 0; q < 16; ++q) {
                int e0 = 2*q, e1 = 2*q + 1;
                float ta = tanhE(fmaf(r1, u0c1[e0], ti0v[e0] + tj0v[e0]));
                float tb = tanhE(fmaf(r1, u0c1[e1], ti0v[e1] + tj0v[e1]));
                w[q] = cvtpk(ta, tb);
            }
            unsigned a10[4], a11[4], a20[4], a21[4];
            #pragma unroll
            for (int v = 0; v < 4; ++v) {
                u32x2 ra = __builtin_amdgcn_permlane32_swap(w[v],   w[4+v],  false, false);
                a10[v] = ra[0]; a11[v] = ra[1];
                u32x2 rb = __builtin_amdgcn_permlane32_swap(w[8+v], w[12+v], false, false);
                a20[v] = rb[0]; a21[v] = rb[1];
            }
            float tj1v = sm[TJ1 + j*36 + n];
            f32x16 acc0, acc1;
            #pragma unroll
            for (int r = 0; r < 16; ++r) {
                acc0[r] = ti1a[r] + tj1v;
                acc1[r] = ti1b[r] + tj1v;
            }
            acc0 = MFMA(frag4(a10[0],a10[1],a10[2],a10[3]), B1f, acc0);
            acc0 = MFMA(frag4(a20[0],a20[1],a20[2],a20[3]), B2f, acc0);
            acc1 = MFMA(frag4(a11[0],a11[1],a11[2],a11[3]), B1f, acc1);
            acc1 = MFMA(frag4(a21[0],a21[1],a21[2],a21[3]), B2f, acc1);
            #pragma unroll
            for (int r = 0; r < 16; ++r) {
                int m = (r&3) + 8*(r>>2) + 4*h;
                float t1a = tanhE(acc0[r]);
                float t1b = tanhE(acc1[r]);
                S1a[r] += t1a;
                S1b[r] += t1b;
                if (j > m)      t1acc0 += t1a;
                if (j > 32 + m) t1acc1 += t1b;
            }
        }
        __syncthreads();                 // all waves done with TI0/TJ0/TI1/TJ1

        {
            float tf = t1acc0 + t1acc1;
            tf += __shfl_xor(tf, 32, 64);
            if (i < 32) sm[PART + c*33 + i] = tf;
        }
        for (int cc = 0; cc < 4; ++cc) {          // S1 -> SS
            if (c == cc) {
                #pragma unroll
                for (int r = 0; r < 16; ++r) {
                    int m = (r&3) + 8*(r>>2) + 4*h;
                    if (cc == 0) {
                        sm[SS + m*33 + n]        = S1a[r];
                        sm[SS + (32+m)*33 + n]   = S1b[r];
                    } else {
                        sm[SS + m*33 + n]       += S1a[r];
                        sm[SS + (32+m)*33 + n]  += S1b[r];
                    }
                }
            }
            __syncthreads();
        }
        if (tid < 32) {
            sm[T1F + tid] = sm[PART + tid] + sm[PART + 33 + tid]
                          + sm[PART + 66 + tid] + sm[PART + 99 + tid];
        }
        __syncthreads();
    }

    // ---- node update 1: hv2 = nu1(hv1, R1@S + rb1) -> MM ----
    for (int out = tid; out < 2048; out += 256) {
        int nn = out >> 5, a = out & 31;
        float acc = rb1[a];
        #pragma unroll
        for (int k = 0; k < 32; ++k) acc += sm[SS + nn*33 + k]*R1T[k*32 + a];
        sm[MM + nn*33 + a] = acc;
    }
    __syncthreads();
    for (int out = tid; out < 2048; out += 256) {
        int nn = out >> 5, hh = out & 31;
        float acc = nu_b1[32 + hh]*C2LOG2E;
        #pragma unroll
        for (int k = 0; k < 32; ++k) acc += sm[HV + nn*33 + k]*W1T1[k*32 + hh];
        #pragma unroll
        for (int k = 0; k < 32; ++k) acc += sm[MM + nn*33 + k]*W1T1[(32+k)*32 + hh];
        sm[HD + nn*33 + hh] = tanhE(acc);
    }
    __syncthreads();
    for (int out = tid; out < 2048; out += 256) {
        int nn = out >> 5, oo = out & 31;
        float acc = nu_b2[32 + oo];
        #pragma unroll
        for (int k = 0; k < 32; ++k) acc += sm[HD + nn*33 + k]*W2T1[k*32 + oo];
        sm[MM + nn*33 + oo] = acc;                 // MM now holds hv2
    }
    __syncthreads();

    // ---- dx output + hvm partials ----
    if (tid < 128) {
        int nn = tid >> 1, d = tid & 1;
        float scale = log1pf(__expf(bf_scale[0]));
        float a = 0.f;
        #pragma unroll
        for (int k = 0; k < 32; ++k) a += sm[MM + nn*33 + k]*dx_W[d*32 + k];
        dx_out[(b*64 + nn)*2 + d] = scale*ftanh(a);
    }
    {
        int e = tid & 31, g = tid >> 5;
        float p = 0.f;
        #pragma unroll
        for (int r = 0; r < 8; ++r) p += sm[MM + (g*8 + r)*33 + e];
        sm[PART + g*33 + e] = p;
    }
    __syncthreads();
    if (tid < 32) {
        float s = 0.f;
        #pragma unroll
        for (int g = 0; g < 8; ++g) s += sm[PART + g*33 + tid];
        sm[HVM + tid] = s*(1.0f/64.0f);
        float he = 0.f;
        #pragma unroll
        for (int k = 0; k < 32; ++k) he += eu_W2[1024 + tid*32 + k]*sm[T1F + k];
        sm[HEM + tid] = he*(1.0f/2016.0f) + eu_b2[32 + tid];
    }

    // ---- pair statistics + f head ----
    float rsum = 0.f, cusp = 0.f, env = 0.f;
    for (int idx = tid; idx < 4096; idx += 256) {
        int ii = idx >> 6, jj = idx & 63;
        if (ii < jj) {
            float d0 = sm[X + ii*2] - sm[X + jj*2];
            float d1 = sm[X + ii*2 + 1] - sm[X + jj*2 + 1];
            float r2 = d0*d0 + d1*d1;
            rsum += sqrtf(r2 + 1e-12f);
            float rp = sqrtf(r2 + 1e-30f);
            float gamma = (sp[ii] == sp[jj]) ? GAMMA_PARA : GAMMA_APARA;
            cusp += gamma*rp/(1.0f + rp*SQRT_OMEGA);
        }
    }
    if (tid < 128) { float v = sm[X + tid]; env = v*v; }

    auto blockReduce = [&](float v) -> float {
        sm[RED + tid] = v; __syncthreads();
        for (int s = 128; s > 0; s >>= 1) {
            if (tid < s) sm[RED + tid] += sm[RED + tid + s];
            __syncthreads();
        }
        float r = sm[RED]; __syncthreads(); return r;
    };
    float rtot = blockReduce(rsum);
    float ctot = blockReduce(cusp);
    float etot = blockReduce(env);

    if (tid < 16) {
        float r2m = rtot*(1.0f/2016.0f);
        float envelope = __expf(-0.5f*etot/ELL2);
        float acc = f_b1[tid];
        #pragma unroll
        for (int m2 = 0; m2 < 32; ++m2) acc += sm[HVM + m2]*f_W1[tid*65 + m2];
        #pragma unroll
        for (int m2 = 0; m2 < 32; ++m2) acc += sm[HEM + m2]*f_W1[tid*65 + 32 + m2];
        acc += r2m*f_W1[tid*65 + 64];
        float v = ftanh(acc)*f_W2[tid];
        v += __shfl_xor(v, 8, 64);
        v += __shfl_xor(v, 4, 64);
        v += __shfl_xor(v, 2, 64);
        v += __shfl_xor(v, 1, 64);
        if (tid == 0) f_out[b] = (v + f_b2[0])*envelope + 0.2f*ctot;
    }
}

extern "C" void kernel_launch(void* const* d_in, const int* in_sizes, int n_in,
                              void* d_out, int out_size, void* d_ws, size_t ws_size,
                              hipStream_t stream)
{
    (void)in_sizes; (void)n_in; (void)out_size; (void)ws_size;
    const float* x         = (const float*)d_in[0];
    const int*   spin      = (const int*)d_in[1];
    const float* node_W    = (const float*)d_in[2];
    const float* edge_W    = (const float*)d_in[3];
    const float* rho_ve_W  = (const float*)d_in[4];
    const float* eu_W1     = (const float*)d_in[5];
    const float* eu_b1     = (const float*)d_in[6];
    const float* eu_W2     = (const float*)d_in[7];
    const float* eu_b2     = (const float*)d_in[8];
    const float* rho_ev_W  = (const float*)d_in[9];
    const float* nu_W1     = (const float*)d_in[10];
    const float* nu_b1     = (const float*)d_in[11];
    const float* nu_W2     = (const float*)d_in[12];
    const float* nu_b2     = (const float*)d_in[13];
    const float* dx_W      = (const float*)d_in[14];
    const float* bf_scale  = (const float*)d_in[15];
    const float* f_W1      = (const float*)d_in[16];
    const float* f_b1      = (const float*)d_in[17];
    const float* f_W2      = (const float*)d_in[18];
    const float* f_b2      = (const float*)d_in[19];

    float* ws    = (float*)d_ws;
    float* MiT0  = ws;                       // 1024 each
    float* MjT0  = MiT0 + 1024;
    float* NiT1  = MjT0 + 1024;
    float* NjT1  = NiT1 + 1024;
    float* K1T   = NjT1 + 1024;
    float* R0T   = K1T  + 1024;
    float* R1T   = R0T  + 1024;
    float* W1T0  = R1T  + 1024;              // 2048 each
    float* W1T1  = W1T0 + 2048;
    float* W2T0  = W1T1 + 2048;              // 1024 each
    float* W2T1  = W2T0 + 1024;
    float* rb0   = W2T1 + 1024;              // 32
    float* rb1   = rb0  + 32;                // 32
    float* u0c1  = rb1  + 32;                // 64

    float* dxout = (float*)d_out;
    float* fout  = dxout + 512*64*2;

    k_weights<<<4, 256, 0, stream>>>(edge_W, rho_ve_W, eu_W1, eu_W2, eu_b2, rho_ev_W,
                                     nu_W1, nu_W2,
                                     MiT0, MjT0, NiT1, NjT1, K1T, R0T, R1T,
                                     rb0, rb1, u0c1, W1T0, W1T1, W2T0, W2T1);
    k_fused<<<512, 256, 0, stream>>>(x, spin, node_W, eu_b1, eu_W2, eu_b2,
                                     MiT0, MjT0, NiT1, NjT1, K1T, u0c1,
                                     R0T, R1T, rb0, rb1, W1T0, W1T1, W2T0, W2T1,
                                     nu_b1, nu_b2, dx_W, bf_scale,
                                     f_W1, f_b1, f_W2, f_b2, dxout, fout);
}